// Round 14
// baseline (4649.707 us; speedup 1.0000x reference)
//
#include <hip/hip_runtime.h>
#include <math.h>

#define N_NODES 1024
#define HID 64
#define BATCH 16
#define TSTEPS 288
#define PWIN 24
#define PL 12
#define EMB 16
#define HOR 12

typedef __attribute__((ext_vector_type(4))) short short4_t;
typedef _Float16 f16x8 __attribute__((ext_vector_type(8)));
typedef _Float16 f16x4 __attribute__((ext_vector_type(4)));
typedef float f32x4 __attribute__((ext_vector_type(4)));

// block per (ngrp, p): lane = n (coalesced 128B stores), wave wid covers b = 4*wid..+3.
// Single pass (f16 output): x[p][j=b*64+h][n] f16.
__global__ __launch_bounds__(256) void embedq5_k(
    const float* __restrict__ src, const float* __restrict__ vw,
    _Float16* __restrict__ xqT)
{
    int p = blockIdx.y;
    int n0 = blockIdx.x * 64;
    int t = threadIdx.x;
    int lane = t & 63, wid = t >> 6;
    __shared__ float sv[192][64];     // [b*12+tt][n]
    __shared__ float wvs[PL*HID];
    __shared__ float pe[64];
    for (int r = wid; r < 192; r += 4) {
        int b = r / 12, tt = r - b*12;
        sv[r][lane] = src[((size_t)b*TSTEPS + p*PL + tt)*N_NODES + n0 + lane];
    }
    for (int i = t; i < PL*HID; i += 256) wvs[i] = vw[i];
    if (t < 64) {
        float d = expf(-(float)(t & ~1) * (float)(9.210340371976184/64.0));
        float arg = (float)p * d;
        pe[t] = (t & 1) ? cosf(arg) : sinf(arg);
    }
    __syncthreads();
#pragma unroll 1
    for (int bb = 0; bb < 4; ++bb) {
        int b = wid*4 + bb;
        float svr[12];
#pragma unroll
        for (int tt = 0; tt < 12; ++tt) svr[tt] = sv[b*12 + tt][lane];
        _Float16* xp = xqT + ((size_t)p << 20) + (size_t)b*64*1024 + n0 + lane;
#pragma unroll 1
        for (int h0 = 0; h0 < 64; h0 += 8) {
#pragma unroll
            for (int hh = 0; hh < 8; ++hh) {
                int h = h0 + hh;
                float d = pe[h];
#pragma unroll
                for (int tt = 0; tt < 12; ++tt) d += svr[tt] * wvs[tt*HID + h];
                xp[(size_t)h*1024] = (_Float16)d;
            }
        }
    }
}

// A[n][m] = softmax_m(relu(emb[n]·emb[m])), written as plain f16.
__global__ __launch_bounds__(256) void adj_k(const float* __restrict__ emb,
    _Float16* __restrict__ Ahi)
{
    __shared__ float en[EMB];
    __shared__ float red[256];
    int n = blockIdx.x, t = threadIdx.x;
    if (t < EMB) en[t] = emb[n*EMB + t];
    __syncthreads();
    float v[4]; float mx = 0.f;
#pragma unroll
    for (int q = 0; q < 4; ++q) {
        int m = q*256 + t;
        float dot = 0.f;
#pragma unroll
        for (int e = 0; e < EMB; ++e) dot += en[e]*emb[m*EMB + e];
        v[q] = fmaxf(dot, 0.f);
        mx = fmaxf(mx, v[q]);
    }
    red[t] = mx; __syncthreads();
    for (int s2 = 128; s2 > 0; s2 >>= 1) {
        if (t < s2) red[t] = fmaxf(red[t], red[t + s2]);
        __syncthreads();
    }
    mx = red[0]; __syncthreads();
    float sum = 0.f;
#pragma unroll
    for (int q = 0; q < 4; ++q) { v[q] = expf(v[q] - mx); sum += v[q]; }
    red[t] = sum; __syncthreads();
    for (int s2 = 128; s2 > 0; s2 >>= 1) {
        if (t < s2) red[t] += red[t + s2];
        __syncthreads();
    }
    float inv = 1.f / red[0];
#pragma unroll
    for (int q = 0; q < 4; ++q)
        Ahi[(size_t)n*N_NODES + q*256 + t] = (_Float16)(v[q]*inv);
}

// gwT2[e][kc4][OUT][4] <- gwl[e][kc][o]  (input-coalesced read, small scatter write)
template<int OUT>
__global__ __launch_bounds__(256) void wtrans2_k(
    const float* __restrict__ gwl, float* __restrict__ gwT2)
{
    int idx = blockIdx.x*256 + threadIdx.x;   // (e*256+kc)*OUT + o, exact grid
    int o = idx % OUT;
    int rest = idx / OUT;
    int kc = rest & 255;
    int e = rest >> 8;
    gwT2[(((size_t)e*64 + (kc >> 2))*OUT + o)*4 + (kc & 3)] = gwl[idx];
}

// W16[n][kc4][OUT][4] f16 = sum_e emb[n][e]*gwT2[e][kc4][o][kj].
// lane = o (coalesced reads AND stores); g = t/OUT picks kc4 stride; 4 nodes/block.
// Single pass, no amax/scale (f16 direct — R12/R13 proved f16 rounding invisible).
template<int OUT>
__global__ __launch_bounds__(256) void wnodeq3_k(
    const float* __restrict__ emb, const float* __restrict__ gwT2,
    _Float16* __restrict__ W16)
{
    int t = threadIdx.x;
    int n0 = blockIdx.x * 4;
    int y = blockIdx.y;                 // kc4 half: y*32 .. y*32+31
    const int G = 256/OUT;
    int o = t % OUT, g = t / OUT;
    __shared__ float se[4][EMB];
    if (t < 4*EMB) se[t >> 4][t & 15] = emb[(n0 + (t >> 4))*EMB + (t & 15)];
    __syncthreads();
    for (int kc4 = y*32 + g; kc4 < (y+1)*32; kc4 += G) {
        f32x4 s[4];
#pragma unroll
        for (int ng = 0; ng < 4; ++ng) s[ng] = (f32x4){0.f,0.f,0.f,0.f};
        const float* gp = gwT2 + ((size_t)kc4*OUT + o)*4;
#pragma unroll
        for (int e = 0; e < EMB; ++e) {
            f32x4 gv = *(const f32x4*)(gp + (size_t)e*(64*OUT*4));
#pragma unroll
            for (int ng = 0; ng < 4; ++ng) {
                float c = se[ng][e];
                s[ng] += gv * c;
            }
        }
#pragma unroll
        for (int ng = 0; ng < 4; ++ng) {
            f16x4 q;
            q[0] = (_Float16)s[ng][0]; q[1] = (_Float16)s[ng][1];
            q[2] = (_Float16)s[ng][2]; q[3] = (_Float16)s[ng][3];
            *(f16x4*)(W16 + (((size_t)(n0+ng)*64 + kc4)*OUT + o)*4) = q;
        }
    }
}

__global__ __launch_bounds__(256) void bias_k(const float* __restrict__ emb,
                        const float* __restrict__ gbl, float* __restrict__ bn, int OUT)
{
    int idx = blockIdx.x*256 + threadIdx.x;
    if (idx >= N_NODES*OUT) return;
    int n = idx / OUT, o = idx % OUT;
    float s = 0.f;
#pragma unroll
    for (int e = 0; e < EMB; ++e) s += emb[n*EMB + e]*gbl[e*OUT + o];
    bn[idx] = s;
}

// C = A@B via mfma_f32_16x16x32_f16, plain f16, f32 accumulate. All operands
// f16 in memory; B TRANSPOSED [j][m] so staging is a straight f16x8 copy.
//   job 0: B = hT16  -> pAh;  job 1: B = xqT16 -> pAx;  job 2: B = zhT16 -> pAzh
// All jobs split-K=2 (ks halves to out + ks*1M; consumers sum the pair).
// z = zoff + blockIdx.z in 0..5: job = z>>1, ks = z&1.
__global__ __launch_bounds__(256) void gemm16_k(
    const _Float16* __restrict__ Ahi,
    const _Float16* __restrict__ hT16, const _Float16* __restrict__ xqT16p,
    const _Float16* __restrict__ zhT16,
    float* __restrict__ pAh, float* __restrict__ pAx, float* __restrict__ pAzh,
    int zoff)
{
    int z = zoff + blockIdx.z;
    int job = z >> 1, ks = z & 1;
    int kbase = ks << 9;
    float* out = ((job == 0) ? pAh : (job == 1) ? pAx : pAzh) + ((size_t)ks << 20);
    const _Float16* BT16 = (job == 0) ? hT16 : ((job == 1) ? xqT16p : zhT16);
    __shared__ _Float16 Ash[64*72];
    __shared__ _Float16 Bsh[64*72];
    int t = threadIdx.x;
    int l = t & 63, w = t >> 6;
    int wr = w >> 1, wc = w & 1;
    int r0 = blockIdx.y*64, c0 = blockIdx.x*64;
    f32x4 acc[2][2];
#pragma unroll
    for (int i = 0; i < 2; ++i)
#pragma unroll
        for (int j = 0; j < 2; ++j) acc[i][j] = (f32x4){0.f,0.f,0.f,0.f};
    int arow = wr*32 + (l & 15);
    int brow = wc*32 + (l & 15);
    int koff = (l >> 4)*8;
    for (int k0 = kbase; k0 < kbase + 512; k0 += 64) {
        __syncthreads();
#pragma unroll
        for (int c = 0; c < 2; ++c) {
            int id = t + 256*c;
            int row = id >> 3, k8 = id & 7;
            *(f16x8*)(&Ash[row*72 + k8*8]) =
                *(const f16x8*)(&Ahi[(size_t)(r0+row)*1024 + k0 + k8*8]);
            *(f16x8*)(&Bsh[row*72 + k8*8]) =
                *(const f16x8*)(&BT16[(size_t)(c0+row)*1024 + k0 + k8*8]);
        }
        __syncthreads();
#pragma unroll
        for (int kk = 0; kk < 2; ++kk) {
            int ko = kk*32 + koff;
            f16x8 ah0 = *(const f16x8*)(&Ash[(size_t)arow*72 + ko]);
            f16x8 ah1 = *(const f16x8*)(&Ash[(size_t)(arow+16)*72 + ko]);
            f16x8 bh0 = *(const f16x8*)(&Bsh[(size_t)brow*72 + ko]);
            f16x8 bh1 = *(const f16x8*)(&Bsh[(size_t)(brow+16)*72 + ko]);
            acc[0][0] = __builtin_amdgcn_mfma_f32_16x16x32_f16(ah0, bh0, acc[0][0], 0, 0, 0);
            acc[0][1] = __builtin_amdgcn_mfma_f32_16x16x32_f16(ah0, bh1, acc[0][1], 0, 0, 0);
            acc[1][0] = __builtin_amdgcn_mfma_f32_16x16x32_f16(ah1, bh0, acc[1][0], 0, 0, 0);
            acc[1][1] = __builtin_amdgcn_mfma_f32_16x16x32_f16(ah1, bh1, acc[1][1], 0, 0, 0);
        }
    }
    // C/D layout: col = lane&15, row = 4*(lane>>4)+reg  [measured m89/m91]
#pragma unroll
    for (int fr = 0; fr < 2; ++fr)
#pragma unroll
        for (int fc = 0; fc < 2; ++fc) {
            int orow = r0 + wr*32 + fr*16 + ((l >> 4) << 2);
            int ocol = c0 + wc*32 + fc*16 + (l & 15);
#pragma unroll
            for (int i = 0; i < 4; ++i)
                out[(size_t)(orow+i)*1024 + ocol] = acc[fr][fc][i];
        }
}

// zr[n][b][o] = sigmoid([x,h,Ax,Ah]·W(o,:) + bg); writes zhT16[j][n]=z*h.
// Weight f16, coalesced via [n][kc4][128][4] layout; no scale.
template<int FIRST>
__global__ __launch_bounds__(256) void gate_k(
    const _Float16* __restrict__ xqT16p,
    const float* __restrict__ hst, const float* __restrict__ pAx,
    const float* __restrict__ pAh, const _Float16* __restrict__ W16,
    const float* __restrict__ bg,
    float* __restrict__ zr, _Float16* __restrict__ zhT16)
{
    __shared__ float inp[16*256];
    int n = ((blockIdx.x & 7) << 7) | (blockIdx.x >> 3);
    int t = threadIdx.x;
    size_t nb = (size_t)n*1024;
    for (int i = t; i < 1024; i += 256) {
        int b = i >> 6, c = i & 63;
        inp[b*256 + c]       = (float)xqT16p[(size_t)i*1024 + n];
        inp[b*256 + 64 + c]  = FIRST ? 0.f : hst[nb + i];
        inp[b*256 + 128 + c] = pAx[nb + i] + pAx[nb + i + 1048576];
        inp[b*256 + 192 + c] = FIRST ? 0.f : (pAh[nb + i] + pAh[nb + i + 1048576]);
    }
    __syncthreads();
    int o = t & 127, g = t >> 7;
    const _Float16* wp = W16 + (size_t)n*32768 + o*4;   // [n][kc4][128][4]
    float bias = bg[n*128 + o];
    float acc[8];
#pragma unroll
    for (int u = 0; u < 8; ++u) acc[u] = 0.f;
    for (int k0 = 0; k0 < 256; k0 += 4) {
        f16x4 w4 = *(const f16x4*)(wp + (size_t)(k0 >> 2)*512);
        float w0 = (float)w4[0], w1 = (float)w4[1], w2 = (float)w4[2], w3 = (float)w4[3];
#pragma unroll
        for (int u = 0; u < 8; ++u) {
            float4 iv = *(const float4*)(&inp[(g*8 + u)*256 + k0]);
            acc[u] += w0*iv.x + w1*iv.y + w2*iv.z + w3*iv.w;
        }
    }
#pragma unroll
    for (int u = 0; u < 8; ++u) {
        int b = g*8 + u;
        float pre = acc[u] + bias;
        float val = 1.f/(1.f + expf(-pre));
        zr[((size_t)n*16 + b)*128 + o] = val;
        if (!FIRST && o < 64)
            zhT16[(size_t)(b*64 + o)*1024 + n] = (_Float16)(val * inp[b*256 + 64 + o]);
    }
}

// h_new = r*h + (1-r)*tanh([x, z*h, Ax, Azh]·W + bu); writes hst rows (f32),
// hT16 columns (f16), (WX) next-layer xqT16 columns (f16). f16 weights.
template<int FIRST, int WX>
__global__ __launch_bounds__(256) void upd_k(
    _Float16* __restrict__ xqT16p,
    float* __restrict__ hst, const float* __restrict__ pAx,
    const float* __restrict__ pAzh, const float* __restrict__ zr,
    const _Float16* __restrict__ W16,
    const float* __restrict__ bu, _Float16* __restrict__ hT16)
{
    __shared__ float inp[16*256];
    int n = ((blockIdx.x & 7) << 7) | (blockIdx.x >> 3);
    int t = threadIdx.x;
    size_t nb = (size_t)n*1024;
    for (int i = t; i < 1024; i += 256) {
        int b = i >> 6, c = i & 63;
        float hv = FIRST ? 0.f : hst[nb + i];
        float zv = zr[((size_t)n*16 + b)*128 + c];
        inp[b*256 + c]       = (float)xqT16p[(size_t)i*1024 + n];
        inp[b*256 + 64 + c]  = zv * hv;
        inp[b*256 + 128 + c] = pAx[nb + i] + pAx[nb + i + 1048576];
        inp[b*256 + 192 + c] = FIRST ? 0.f : (pAzh[nb + i] + pAzh[nb + i + 1048576]);
    }
    __syncthreads();
    int o = t & 63, g = t >> 6;
    const _Float16* wp = W16 + (size_t)n*16384 + o*4;   // [n][kc4][64][4]
    float bias = bu[n*64 + o];
    float acc[4];
#pragma unroll
    for (int u = 0; u < 4; ++u) acc[u] = 0.f;
    for (int k0 = 0; k0 < 256; k0 += 4) {
        f16x4 w4 = *(const f16x4*)(wp + (size_t)(k0 >> 2)*256);
        float w0 = (float)w4[0], w1 = (float)w4[1], w2 = (float)w4[2], w3 = (float)w4[3];
#pragma unroll
        for (int u = 0; u < 4; ++u) {
            float4 iv = *(const float4*)(&inp[(g*4 + u)*256 + k0]);
            acc[u] += w0*iv.x + w1*iv.y + w2*iv.z + w3*iv.w;
        }
    }
#pragma unroll
    for (int u = 0; u < 4; ++u) {
        int b = g*4 + u;
        float r = zr[((size_t)n*16 + b)*128 + 64 + o];
        float hold = FIRST ? 0.f : hst[nb + b*64 + o];
        float hc = tanhf(acc[u] + bias);
        float hn = r*hold + (1.f - r)*hc;
        hst[nb + b*64 + o] = hn;
        hT16[(size_t)(b*64 + o)*1024 + n] = (_Float16)hn;
        if (WX) xqT16p[(size_t)(b*64 + o)*1024 + n] = (_Float16)hn;
    }
}

// out[b][o][n] = h[n][b][:]·ecw[o][:] + ecb[o]
__global__ __launch_bounds__(256) void endconv_k(
    const float* __restrict__ hst, const float* __restrict__ ecw,
    const float* __restrict__ ecb, float* __restrict__ out)
{
    int idx = blockIdx.x*256 + threadIdx.x;
    int n = idx & 1023;
    int o = (idx >> 10) % HOR;
    int b = idx / (HOR*1024);
    float s = ecb[o];
#pragma unroll
    for (int hh = 0; hh < 64; ++hh)
        s += hst[((size_t)n*16 + b)*64 + hh] * ecw[o*64 + hh];
    out[idx] = s;
}

extern "C" void kernel_launch(void* const* d_in, const int* in_sizes, int n_in,
                              void* d_out, int out_size, void* d_ws, size_t ws_size,
                              hipStream_t stream)
{
    const float* source = (const float*)d_in[0];
    const float* emb    = (const float*)d_in[2];
    const float* vw     = (const float*)d_in[3];
    const float* gate_w = (const float*)d_in[4];
    const float* gate_b = (const float*)d_in[5];
    const float* upd_w  = (const float*)d_in[6];
    const float* upd_b  = (const float*)d_in[7];
    const float* ecw    = (const float*)d_in[8];
    const float* ecb    = (const float*)d_in[9];
    float* out = (float*)d_out;

    // ---- workspace carve: ~151 MB ----
    char* p = (char*)d_ws;
    _Float16* Ahi = (_Float16*)p; p += (size_t)1048576*2;    //   2.0 MB
    _Float16* WgQ = (_Float16*)p; p += (size_t)33554432*2;   //  64.0 MB... f16: 32 MB used
    _Float16* WuQ = (_Float16*)p; p += (size_t)16777216*2;   //  16 MB used (keep stride)
    float* bgn  = (float*)p;  p += (size_t)131072*4;         //   0.5 MB
    float* bun  = (float*)p;  p += (size_t)65536*4;          //   0.25 MB
    _Float16* xqT = (_Float16*)p; p += (size_t)25165824*2;   //  48.0 MB  [p][j][n] f16
    float* hbuf = (float*)p;  p += (size_t)1048576*4;        //   4.0 MB  h rows f32
    _Float16* hT16 = (_Float16*)p; p += (size_t)1048576*2;   //   2.0 MB  h cols f16
    float* zrb  = (float*)p;  p += (size_t)2097152*4;        //   8.0 MB
    _Float16* zhT16 = (_Float16*)p; p += (size_t)1048576*2;  //   2.0 MB  (z*h)^T f16
    float* pAh  = (float*)p;  p += (size_t)2097152*4;        //   8.0 MB  split-K pair
    float* pAx  = (float*)p;  p += (size_t)2097152*4;        //   8.0 MB  split-K pair
    float* pAzh = (float*)p;  p += (size_t)2097152*4;        //   8.0 MB  split-K pair
    float* gwT2 = pAzh;   // 2 MB scratch, aliases pAzh (dead during layer setup)

    embedq5_k<<<dim3(16,24), 256, 0, stream>>>(source, vw, xqT);
    adj_k<<<1024, 256, 0, stream>>>(emb, Ahi);

    for (int l = 0; l < 2; ++l) {
        wtrans2_k<128><<<2048, 256, 0, stream>>>(gate_w + (size_t)l*524288, gwT2);
        wnodeq3_k<128><<<dim3(256,2), 256, 0, stream>>>(emb, gwT2, WgQ);
        wtrans2_k<64><<<1024, 256, 0, stream>>>(upd_w + (size_t)l*262144, gwT2);
        wnodeq3_k<64><<<dim3(256,2), 256, 0, stream>>>(emb, gwT2, WuQ);
        bias_k<<<512, 256, 0, stream>>>(emb, gate_b + l*2048, bgn, 128);
        bias_k<<<256, 256, 0, stream>>>(emb, upd_b + l*1024, bun, 64);
        for (int ps = 0; ps < PWIN; ++ps) {
            _Float16* xqT_p = xqT + ((size_t)ps << 20);
            if (ps == 0) {
                // h == 0: only A@x needed (job 1, both K-halves)
                gemm16_k<<<dim3(16,16,2), 256, 0, stream>>>(Ahi, hT16, xqT_p, zhT16, pAh, pAx, pAzh, 2);
                gate_k<1><<<1024, 256, 0, stream>>>(xqT_p, hbuf, pAx, pAh, WgQ, bgn, zrb, zhT16);
                if (l == 0)
                    upd_k<1,1><<<1024, 256, 0, stream>>>(xqT_p, hbuf, pAx, pAzh, zrb, WuQ, bun, hT16);
                else
                    upd_k<1,0><<<1024, 256, 0, stream>>>(xqT_p, hbuf, pAx, pAzh, zrb, WuQ, bun, hT16);
            } else {
                gemm16_k<<<dim3(16,16,4), 256, 0, stream>>>(Ahi, hT16, xqT_p, zhT16, pAh, pAx, pAzh, 0);
                gate_k<0><<<1024, 256, 0, stream>>>(xqT_p, hbuf, pAx, pAh, WgQ, bgn, zrb, zhT16);
                gemm16_k<<<dim3(16,16,2), 256, 0, stream>>>(Ahi, hT16, xqT_p, zhT16, pAh, pAx, pAzh, 4);
                if (l == 0)
                    upd_k<0,1><<<1024, 256, 0, stream>>>(xqT_p, hbuf, pAx, pAzh, zrb, WuQ, bun, hT16);
                else
                    upd_k<0,0><<<1024, 256, 0, stream>>>(xqT_p, hbuf, pAx, pAzh, zrb, WuQ, bun, hT16);
            }
        }
    }
    endconv_k<<<768, 256, 0, stream>>>(hbuf, ecw, ecb, out);
}

// Round 15
// 4301.948 us; speedup vs baseline: 1.0808x; 1.0808x over previous
//
#include <hip/hip_runtime.h>
#include <math.h>

#define N_NODES 1024
#define HID 64
#define BATCH 16
#define TSTEPS 288
#define PWIN 24
#define PL 12
#define EMB 16
#define HOR 12

typedef __attribute__((ext_vector_type(4))) short short4_t;
typedef _Float16 f16x8 __attribute__((ext_vector_type(8)));
typedef _Float16 f16x4 __attribute__((ext_vector_type(4)));
typedef float f32x4 __attribute__((ext_vector_type(4)));

// block per (ngrp, p): lane = n (coalesced 128B stores), wave wid covers b = 4*wid..+3.
// Single pass (f16 output): x[p][j=b*64+h][n] f16.
__global__ __launch_bounds__(256) void embedq5_k(
    const float* __restrict__ src, const float* __restrict__ vw,
    _Float16* __restrict__ xqT)
{
    int p = blockIdx.y;
    int n0 = blockIdx.x * 64;
    int t = threadIdx.x;
    int lane = t & 63, wid = t >> 6;
    __shared__ float sv[192][64];     // [b*12+tt][n]
    __shared__ float wvs[PL*HID];
    __shared__ float pe[64];
    for (int r = wid; r < 192; r += 4) {
        int b = r / 12, tt = r - b*12;
        sv[r][lane] = src[((size_t)b*TSTEPS + p*PL + tt)*N_NODES + n0 + lane];
    }
    for (int i = t; i < PL*HID; i += 256) wvs[i] = vw[i];
    if (t < 64) {
        float d = expf(-(float)(t & ~1) * (float)(9.210340371976184/64.0));
        float arg = (float)p * d;
        pe[t] = (t & 1) ? cosf(arg) : sinf(arg);
    }
    __syncthreads();
#pragma unroll 1
    for (int bb = 0; bb < 4; ++bb) {
        int b = wid*4 + bb;
        float svr[12];
#pragma unroll
        for (int tt = 0; tt < 12; ++tt) svr[tt] = sv[b*12 + tt][lane];
        _Float16* xp = xqT + ((size_t)p << 20) + (size_t)b*64*1024 + n0 + lane;
#pragma unroll 1
        for (int h0 = 0; h0 < 64; h0 += 8) {
#pragma unroll
            for (int hh = 0; hh < 8; ++hh) {
                int h = h0 + hh;
                float d = pe[h];
#pragma unroll
                for (int tt = 0; tt < 12; ++tt) d += svr[tt] * wvs[tt*HID + h];
                xp[(size_t)h*1024] = (_Float16)d;
            }
        }
    }
}

// A[n][m] = softmax_m(relu(emb[n]·emb[m])), written as plain f16.
__global__ __launch_bounds__(256) void adj_k(const float* __restrict__ emb,
    _Float16* __restrict__ Ahi)
{
    __shared__ float en[EMB];
    __shared__ float red[256];
    int n = blockIdx.x, t = threadIdx.x;
    if (t < EMB) en[t] = emb[n*EMB + t];
    __syncthreads();
    float v[4]; float mx = 0.f;
#pragma unroll
    for (int q = 0; q < 4; ++q) {
        int m = q*256 + t;
        float dot = 0.f;
#pragma unroll
        for (int e = 0; e < EMB; ++e) dot += en[e]*emb[m*EMB + e];
        v[q] = fmaxf(dot, 0.f);
        mx = fmaxf(mx, v[q]);
    }
    red[t] = mx; __syncthreads();
    for (int s2 = 128; s2 > 0; s2 >>= 1) {
        if (t < s2) red[t] = fmaxf(red[t], red[t + s2]);
        __syncthreads();
    }
    mx = red[0]; __syncthreads();
    float sum = 0.f;
#pragma unroll
    for (int q = 0; q < 4; ++q) { v[q] = expf(v[q] - mx); sum += v[q]; }
    red[t] = sum; __syncthreads();
    for (int s2 = 128; s2 > 0; s2 >>= 1) {
        if (t < s2) red[t] += red[t + s2];
        __syncthreads();
    }
    float inv = 1.f / red[0];
#pragma unroll
    for (int q = 0; q < 4; ++q)
        Ahi[(size_t)n*N_NODES + q*256 + t] = (_Float16)(v[q]*inv);
}

// gwT2[e][kc4][OUT][4] <- gwl[e][kc][o]  (input-coalesced read, small scatter write)
template<int OUT>
__global__ __launch_bounds__(256) void wtrans2_k(
    const float* __restrict__ gwl, float* __restrict__ gwT2)
{
    int idx = blockIdx.x*256 + threadIdx.x;   // (e*256+kc)*OUT + o, exact grid
    int o = idx % OUT;
    int rest = idx / OUT;
    int kc = rest & 255;
    int e = rest >> 8;
    gwT2[(((size_t)e*64 + (kc >> 2))*OUT + o)*4 + (kc & 3)] = gwl[idx];
}

// W16[n][kc4][OUT][4] f16 = sum_e emb[n][e]*gwT2[e][kc4][o][kj].
// lane = o (coalesced reads AND stores); grid (256, 8) -> 2048 blocks (8/CU),
// e-loop unroll capped at 4 to keep VGPR < ~96 (R14 post-mortem: full unroll
// hit 180 VGPR, 11% occupancy, latency-bound at 151 us).
template<int OUT>
__global__ __launch_bounds__(256) void wnodeq3_k(
    const float* __restrict__ emb, const float* __restrict__ gwT2,
    _Float16* __restrict__ W16)
{
    int t = threadIdx.x;
    int n0 = blockIdx.x * 4;
    int y = blockIdx.y;                 // kc4 range: y*8 .. y*8+7
    const int G = 256/OUT;
    int o = t % OUT, g = t / OUT;
    __shared__ float se[4][EMB];
    if (t < 4*EMB) se[t >> 4][t & 15] = emb[(n0 + (t >> 4))*EMB + (t & 15)];
    __syncthreads();
    for (int kc4 = y*8 + g; kc4 < (y+1)*8; kc4 += G) {
        f32x4 s[4];
#pragma unroll
        for (int ng = 0; ng < 4; ++ng) s[ng] = (f32x4){0.f,0.f,0.f,0.f};
        const float* gp = gwT2 + ((size_t)kc4*OUT + o)*4;
#pragma unroll 4
        for (int e = 0; e < EMB; ++e) {
            f32x4 gv = *(const f32x4*)(gp + (size_t)e*(64*OUT*4));
#pragma unroll
            for (int ng = 0; ng < 4; ++ng) {
                float c = se[ng][e];
                s[ng] += gv * c;
            }
        }
#pragma unroll
        for (int ng = 0; ng < 4; ++ng) {
            f16x4 q;
            q[0] = (_Float16)s[ng][0]; q[1] = (_Float16)s[ng][1];
            q[2] = (_Float16)s[ng][2]; q[3] = (_Float16)s[ng][3];
            *(f16x4*)(W16 + (((size_t)(n0+ng)*64 + kc4)*OUT + o)*4) = q;
        }
    }
}

__global__ __launch_bounds__(256) void bias_k(const float* __restrict__ emb,
                        const float* __restrict__ gbl, float* __restrict__ bn, int OUT)
{
    int idx = blockIdx.x*256 + threadIdx.x;
    if (idx >= N_NODES*OUT) return;
    int n = idx / OUT, o = idx % OUT;
    float s = 0.f;
#pragma unroll
    for (int e = 0; e < EMB; ++e) s += emb[n*EMB + e]*gbl[e*OUT + o];
    bn[idx] = s;
}

// C = A@B via mfma_f32_16x16x32_f16, plain f16, f32 accumulate. All operands
// f16 in memory; B TRANSPOSED [j][m] so staging is a straight f16x8 copy.
//   job 0: B = hT16  -> pAh;  job 1: B = xqT16 -> pAx;  job 2: B = zhT16 -> pAzh
// All jobs split-K=2 (ks halves to out + ks*1M; consumers sum the pair).
// z = zoff + blockIdx.z in 0..5: job = z>>1, ks = z&1.
__global__ __launch_bounds__(256) void gemm16_k(
    const _Float16* __restrict__ Ahi,
    const _Float16* __restrict__ hT16, const _Float16* __restrict__ xqT16p,
    const _Float16* __restrict__ zhT16,
    float* __restrict__ pAh, float* __restrict__ pAx, float* __restrict__ pAzh,
    int zoff)
{
    int z = zoff + blockIdx.z;
    int job = z >> 1, ks = z & 1;
    int kbase = ks << 9;
    float* out = ((job == 0) ? pAh : (job == 1) ? pAx : pAzh) + ((size_t)ks << 20);
    const _Float16* BT16 = (job == 0) ? hT16 : ((job == 1) ? xqT16p : zhT16);
    __shared__ _Float16 Ash[64*72];
    __shared__ _Float16 Bsh[64*72];
    int t = threadIdx.x;
    int l = t & 63, w = t >> 6;
    int wr = w >> 1, wc = w & 1;
    int r0 = blockIdx.y*64, c0 = blockIdx.x*64;
    f32x4 acc[2][2];
#pragma unroll
    for (int i = 0; i < 2; ++i)
#pragma unroll
        for (int j = 0; j < 2; ++j) acc[i][j] = (f32x4){0.f,0.f,0.f,0.f};
    int arow = wr*32 + (l & 15);
    int brow = wc*32 + (l & 15);
    int koff = (l >> 4)*8;
    for (int k0 = kbase; k0 < kbase + 512; k0 += 64) {
        __syncthreads();
#pragma unroll
        for (int c = 0; c < 2; ++c) {
            int id = t + 256*c;
            int row = id >> 3, k8 = id & 7;
            *(f16x8*)(&Ash[row*72 + k8*8]) =
                *(const f16x8*)(&Ahi[(size_t)(r0+row)*1024 + k0 + k8*8]);
            *(f16x8*)(&Bsh[row*72 + k8*8]) =
                *(const f16x8*)(&BT16[(size_t)(c0+row)*1024 + k0 + k8*8]);
        }
        __syncthreads();
#pragma unroll
        for (int kk = 0; kk < 2; ++kk) {
            int ko = kk*32 + koff;
            f16x8 ah0 = *(const f16x8*)(&Ash[(size_t)arow*72 + ko]);
            f16x8 ah1 = *(const f16x8*)(&Ash[(size_t)(arow+16)*72 + ko]);
            f16x8 bh0 = *(const f16x8*)(&Bsh[(size_t)brow*72 + ko]);
            f16x8 bh1 = *(const f16x8*)(&Bsh[(size_t)(brow+16)*72 + ko]);
            acc[0][0] = __builtin_amdgcn_mfma_f32_16x16x32_f16(ah0, bh0, acc[0][0], 0, 0, 0);
            acc[0][1] = __builtin_amdgcn_mfma_f32_16x16x32_f16(ah0, bh1, acc[0][1], 0, 0, 0);
            acc[1][0] = __builtin_amdgcn_mfma_f32_16x16x32_f16(ah1, bh0, acc[1][0], 0, 0, 0);
            acc[1][1] = __builtin_amdgcn_mfma_f32_16x16x32_f16(ah1, bh1, acc[1][1], 0, 0, 0);
        }
    }
    // C/D layout: col = lane&15, row = 4*(lane>>4)+reg  [measured m89/m91]
#pragma unroll
    for (int fr = 0; fr < 2; ++fr)
#pragma unroll
        for (int fc = 0; fc < 2; ++fc) {
            int orow = r0 + wr*32 + fr*16 + ((l >> 4) << 2);
            int ocol = c0 + wc*32 + fc*16 + (l & 15);
#pragma unroll
            for (int i = 0; i < 4; ++i)
                out[(size_t)(orow+i)*1024 + ocol] = acc[fr][fc][i];
        }
}

// zr[n][b][o] = sigmoid([x,h,Ax,Ah]·W(o,:) + bg); writes zhT16[j][n]=z*h.
// Weight f16, coalesced via [n][kc4][128][4] layout; no scale.
template<int FIRST>
__global__ __launch_bounds__(256) void gate_k(
    const _Float16* __restrict__ xqT16p,
    const float* __restrict__ hst, const float* __restrict__ pAx,
    const float* __restrict__ pAh, const _Float16* __restrict__ W16,
    const float* __restrict__ bg,
    float* __restrict__ zr, _Float16* __restrict__ zhT16)
{
    __shared__ float inp[16*256];
    int n = ((blockIdx.x & 7) << 7) | (blockIdx.x >> 3);
    int t = threadIdx.x;
    size_t nb = (size_t)n*1024;
    for (int i = t; i < 1024; i += 256) {
        int b = i >> 6, c = i & 63;
        inp[b*256 + c]       = (float)xqT16p[(size_t)i*1024 + n];
        inp[b*256 + 64 + c]  = FIRST ? 0.f : hst[nb + i];
        inp[b*256 + 128 + c] = pAx[nb + i] + pAx[nb + i + 1048576];
        inp[b*256 + 192 + c] = FIRST ? 0.f : (pAh[nb + i] + pAh[nb + i + 1048576]);
    }
    __syncthreads();
    int o = t & 127, g = t >> 7;
    const _Float16* wp = W16 + (size_t)n*32768 + o*4;   // [n][kc4][128][4]
    float bias = bg[n*128 + o];
    float acc[8];
#pragma unroll
    for (int u = 0; u < 8; ++u) acc[u] = 0.f;
    for (int k0 = 0; k0 < 256; k0 += 4) {
        f16x4 w4 = *(const f16x4*)(wp + (size_t)(k0 >> 2)*512);
        float w0 = (float)w4[0], w1 = (float)w4[1], w2 = (float)w4[2], w3 = (float)w4[3];
#pragma unroll
        for (int u = 0; u < 8; ++u) {
            float4 iv = *(const float4*)(&inp[(g*8 + u)*256 + k0]);
            acc[u] += w0*iv.x + w1*iv.y + w2*iv.z + w3*iv.w;
        }
    }
#pragma unroll
    for (int u = 0; u < 8; ++u) {
        int b = g*8 + u;
        float pre = acc[u] + bias;
        float val = 1.f/(1.f + expf(-pre));
        zr[((size_t)n*16 + b)*128 + o] = val;
        if (!FIRST && o < 64)
            zhT16[(size_t)(b*64 + o)*1024 + n] = (_Float16)(val * inp[b*256 + 64 + o]);
    }
}

// h_new = r*h + (1-r)*tanh([x, z*h, Ax, Azh]·W + bu); writes hst rows (f32),
// hT16 columns (f16), (WX) next-layer xqT16 columns (f16). f16 weights.
template<int FIRST, int WX>
__global__ __launch_bounds__(256) void upd_k(
    _Float16* __restrict__ xqT16p,
    float* __restrict__ hst, const float* __restrict__ pAx,
    const float* __restrict__ pAzh, const float* __restrict__ zr,
    const _Float16* __restrict__ W16,
    const float* __restrict__ bu, _Float16* __restrict__ hT16)
{
    __shared__ float inp[16*256];
    int n = ((blockIdx.x & 7) << 7) | (blockIdx.x >> 3);
    int t = threadIdx.x;
    size_t nb = (size_t)n*1024;
    for (int i = t; i < 1024; i += 256) {
        int b = i >> 6, c = i & 63;
        float hv = FIRST ? 0.f : hst[nb + i];
        float zv = zr[((size_t)n*16 + b)*128 + c];
        inp[b*256 + c]       = (float)xqT16p[(size_t)i*1024 + n];
        inp[b*256 + 64 + c]  = zv * hv;
        inp[b*256 + 128 + c] = pAx[nb + i] + pAx[nb + i + 1048576];
        inp[b*256 + 192 + c] = FIRST ? 0.f : (pAzh[nb + i] + pAzh[nb + i + 1048576]);
    }
    __syncthreads();
    int o = t & 63, g = t >> 6;
    const _Float16* wp = W16 + (size_t)n*16384 + o*4;   // [n][kc4][64][4]
    float bias = bu[n*64 + o];
    float acc[4];
#pragma unroll
    for (int u = 0; u < 4; ++u) acc[u] = 0.f;
    for (int k0 = 0; k0 < 256; k0 += 4) {
        f16x4 w4 = *(const f16x4*)(wp + (size_t)(k0 >> 2)*256);
        float w0 = (float)w4[0], w1 = (float)w4[1], w2 = (float)w4[2], w3 = (float)w4[3];
#pragma unroll
        for (int u = 0; u < 4; ++u) {
            float4 iv = *(const float4*)(&inp[(g*4 + u)*256 + k0]);
            acc[u] += w0*iv.x + w1*iv.y + w2*iv.z + w3*iv.w;
        }
    }
#pragma unroll
    for (int u = 0; u < 4; ++u) {
        int b = g*4 + u;
        float r = zr[((size_t)n*16 + b)*128 + 64 + o];
        float hold = FIRST ? 0.f : hst[nb + b*64 + o];
        float hc = tanhf(acc[u] + bias);
        float hn = r*hold + (1.f - r)*hc;
        hst[nb + b*64 + o] = hn;
        hT16[(size_t)(b*64 + o)*1024 + n] = (_Float16)hn;
        if (WX) xqT16p[(size_t)(b*64 + o)*1024 + n] = (_Float16)hn;
    }
}

// out[b][o][n] = h[n][b][:]·ecw[o][:] + ecb[o]
__global__ __launch_bounds__(256) void endconv_k(
    const float* __restrict__ hst, const float* __restrict__ ecw,
    const float* __restrict__ ecb, float* __restrict__ out)
{
    int idx = blockIdx.x*256 + threadIdx.x;
    int n = idx & 1023;
    int o = (idx >> 10) % HOR;
    int b = idx / (HOR*1024);
    float s = ecb[o];
#pragma unroll
    for (int hh = 0; hh < 64; ++hh)
        s += hst[((size_t)n*16 + b)*64 + hh] * ecw[o*64 + hh];
    out[idx] = s;
}

extern "C" void kernel_launch(void* const* d_in, const int* in_sizes, int n_in,
                              void* d_out, int out_size, void* d_ws, size_t ws_size,
                              hipStream_t stream)
{
    const float* source = (const float*)d_in[0];
    const float* emb    = (const float*)d_in[2];
    const float* vw     = (const float*)d_in[3];
    const float* gate_w = (const float*)d_in[4];
    const float* gate_b = (const float*)d_in[5];
    const float* upd_w  = (const float*)d_in[6];
    const float* upd_b  = (const float*)d_in[7];
    const float* ecw    = (const float*)d_in[8];
    const float* ecb    = (const float*)d_in[9];
    float* out = (float*)d_out;

    // ---- workspace carve: ~151 MB ----
    char* p = (char*)d_ws;
    _Float16* Ahi = (_Float16*)p; p += (size_t)1048576*2;    //   2.0 MB
    _Float16* WgQ = (_Float16*)p; p += (size_t)33554432*2;   //  64.0 MB slot (32 MB used)
    _Float16* WuQ = (_Float16*)p; p += (size_t)16777216*2;   //  32.0 MB slot (16 MB used)
    float* bgn  = (float*)p;  p += (size_t)131072*4;         //   0.5 MB
    float* bun  = (float*)p;  p += (size_t)65536*4;          //   0.25 MB
    _Float16* xqT = (_Float16*)p; p += (size_t)25165824*2;   //  48.0 MB  [p][j][n] f16
    float* hbuf = (float*)p;  p += (size_t)1048576*4;        //   4.0 MB  h rows f32
    _Float16* hT16 = (_Float16*)p; p += (size_t)1048576*2;   //   2.0 MB  h cols f16
    float* zrb  = (float*)p;  p += (size_t)2097152*4;        //   8.0 MB
    _Float16* zhT16 = (_Float16*)p; p += (size_t)1048576*2;  //   2.0 MB  (z*h)^T f16
    float* pAh  = (float*)p;  p += (size_t)2097152*4;        //   8.0 MB  split-K pair
    float* pAx  = (float*)p;  p += (size_t)2097152*4;        //   8.0 MB  split-K pair
    float* pAzh = (float*)p;  p += (size_t)2097152*4;        //   8.0 MB  split-K pair
    float* gwT2 = pAzh;   // 2 MB scratch, aliases pAzh (dead during layer setup)

    embedq5_k<<<dim3(16,24), 256, 0, stream>>>(source, vw, xqT);
    adj_k<<<1024, 256, 0, stream>>>(emb, Ahi);

    for (int l = 0; l < 2; ++l) {
        wtrans2_k<128><<<2048, 256, 0, stream>>>(gate_w + (size_t)l*524288, gwT2);
        wnodeq3_k<128><<<dim3(256,8), 256, 0, stream>>>(emb, gwT2, WgQ);
        wtrans2_k<64><<<1024, 256, 0, stream>>>(upd_w + (size_t)l*262144, gwT2);
        wnodeq3_k<64><<<dim3(256,8), 256, 0, stream>>>(emb, gwT2, WuQ);
        bias_k<<<512, 256, 0, stream>>>(emb, gate_b + l*2048, bgn, 128);
        bias_k<<<256, 256, 0, stream>>>(emb, upd_b + l*1024, bun, 64);
        for (int ps = 0; ps < PWIN; ++ps) {
            _Float16* xqT_p = xqT + ((size_t)ps << 20);
            if (ps == 0) {
                // h == 0: only A@x needed (job 1, both K-halves)
                gemm16_k<<<dim3(16,16,2), 256, 0, stream>>>(Ahi, hT16, xqT_p, zhT16, pAh, pAx, pAzh, 2);
                gate_k<1><<<1024, 256, 0, stream>>>(xqT_p, hbuf, pAx, pAh, WgQ, bgn, zrb, zhT16);
                if (l == 0)
                    upd_k<1,1><<<1024, 256, 0, stream>>>(xqT_p, hbuf, pAx, pAzh, zrb, WuQ, bun, hT16);
                else
                    upd_k<1,0><<<1024, 256, 0, stream>>>(xqT_p, hbuf, pAx, pAzh, zrb, WuQ, bun, hT16);
            } else {
                gemm16_k<<<dim3(16,16,4), 256, 0, stream>>>(Ahi, hT16, xqT_p, zhT16, pAh, pAx, pAzh, 0);
                gate_k<0><<<1024, 256, 0, stream>>>(xqT_p, hbuf, pAx, pAh, WgQ, bgn, zrb, zhT16);
                gemm16_k<<<dim3(16,16,2), 256, 0, stream>>>(Ahi, hT16, xqT_p, zhT16, pAh, pAx, pAzh, 4);
                if (l == 0)
                    upd_k<0,1><<<1024, 256, 0, stream>>>(xqT_p, hbuf, pAx, pAzh, zrb, WuQ, bun, hT16);
                else
                    upd_k<0,0><<<1024, 256, 0, stream>>>(xqT_p, hbuf, pAx, pAzh, zrb, WuQ, bun, hT16);
            }
        }
    }
    endconv_k<<<768, 256, 0, stream>>>(hbuf, ecw, ecb, out);
}

// Round 16
// 4282.399 us; speedup vs baseline: 1.0858x; 1.0046x over previous
//
#include <hip/hip_runtime.h>
#include <math.h>

#define N_NODES 1024
#define HID 64
#define BATCH 16
#define TSTEPS 288
#define PWIN 24
#define PL 12
#define EMB 16
#define HOR 12

typedef __attribute__((ext_vector_type(4))) short short4_t;
typedef _Float16 f16x8 __attribute__((ext_vector_type(8)));
typedef _Float16 f16x4 __attribute__((ext_vector_type(4)));
typedef float f32x4 __attribute__((ext_vector_type(4)));

// block per (ngrp, p, bhalf): lane = n (coalesced 128B stores); 8 b's per block,
// wave wid covers 2 b's. LDS 28KB -> 5 blocks/CU (R15: 52KB, 3/CU, 59us).
__global__ __launch_bounds__(256) void embedq6_k(
    const float* __restrict__ src, const float* __restrict__ vw,
    _Float16* __restrict__ xqT)
{
    int p = blockIdx.y;
    int n0 = blockIdx.x * 64;
    int bh = blockIdx.z;              // b in [bh*8, bh*8+8)
    int t = threadIdx.x;
    int lane = t & 63, wid = t >> 6;
    __shared__ float sv[96][64];      // [(b-bh*8)*12+tt][n]
    __shared__ float wvs[PL*HID];
    __shared__ float pe[64];
    for (int r = wid; r < 96; r += 4) {
        int b = bh*8 + r/12, tt = r % 12;
        sv[r][lane] = src[((size_t)b*TSTEPS + p*PL + tt)*N_NODES + n0 + lane];
    }
    for (int i = t; i < PL*HID; i += 256) wvs[i] = vw[i];
    if (t < 64) {
        float d = expf(-(float)(t & ~1) * (float)(9.210340371976184/64.0));
        float arg = (float)p * d;
        pe[t] = (t & 1) ? cosf(arg) : sinf(arg);
    }
    __syncthreads();
#pragma unroll 1
    for (int bb = 0; bb < 2; ++bb) {
        int br = wid*2 + bb;          // 0..7 within block
        int b = bh*8 + br;
        float svr[12];
#pragma unroll
        for (int tt = 0; tt < 12; ++tt) svr[tt] = sv[br*12 + tt][lane];
        _Float16* xp = xqT + ((size_t)p << 20) + (size_t)b*64*1024 + n0 + lane;
#pragma unroll 1
        for (int h0 = 0; h0 < 64; h0 += 8) {
#pragma unroll
            for (int hh = 0; hh < 8; ++hh) {
                int h = h0 + hh;
                float d = pe[h];
#pragma unroll
                for (int tt = 0; tt < 12; ++tt) d += svr[tt] * wvs[tt*HID + h];
                xp[(size_t)h*1024] = (_Float16)d;
            }
        }
    }
}

// A[n][m] = softmax_m(relu(emb[n]·emb[m])), written as plain f16.
__global__ __launch_bounds__(256) void adj_k(const float* __restrict__ emb,
    _Float16* __restrict__ Ahi)
{
    __shared__ float en[EMB];
    __shared__ float red[256];
    int n = blockIdx.x, t = threadIdx.x;
    if (t < EMB) en[t] = emb[n*EMB + t];
    __syncthreads();
    float v[4]; float mx = 0.f;
#pragma unroll
    for (int q = 0; q < 4; ++q) {
        int m = q*256 + t;
        float dot = 0.f;
#pragma unroll
        for (int e = 0; e < EMB; ++e) dot += en[e]*emb[m*EMB + e];
        v[q] = fmaxf(dot, 0.f);
        mx = fmaxf(mx, v[q]);
    }
    red[t] = mx; __syncthreads();
    for (int s2 = 128; s2 > 0; s2 >>= 1) {
        if (t < s2) red[t] = fmaxf(red[t], red[t + s2]);
        __syncthreads();
    }
    mx = red[0]; __syncthreads();
    float sum = 0.f;
#pragma unroll
    for (int q = 0; q < 4; ++q) { v[q] = expf(v[q] - mx); sum += v[q]; }
    red[t] = sum; __syncthreads();
    for (int s2 = 128; s2 > 0; s2 >>= 1) {
        if (t < s2) red[t] += red[t + s2];
        __syncthreads();
    }
    float inv = 1.f / red[0];
#pragma unroll
    for (int q = 0; q < 4; ++q)
        Ahi[(size_t)n*N_NODES + q*256 + t] = (_Float16)(v[q]*inv);
}

// gwT2[e][kc4][OUT][4] <- gwl[e][kc][o]
template<int OUT>
__global__ __launch_bounds__(256) void wtrans2_k(
    const float* __restrict__ gwl, float* __restrict__ gwT2)
{
    int idx = blockIdx.x*256 + threadIdx.x;
    int o = idx % OUT;
    int rest = idx / OUT;
    int kc = rest & 255;
    int e = rest >> 8;
    gwT2[(((size_t)e*64 + (kc >> 2))*OUT + o)*4 + (kc & 3)] = gwl[idx];
}

// W16[n][kc4][OUT][4] f16 = sum_e emb[n][e]*gwT2[e][kc4][o][kj].
// grid (256,8), e-unroll 4 (R14 lesson: full unroll -> 180 VGPR, 11% occ).
template<int OUT>
__global__ __launch_bounds__(256) void wnodeq3_k(
    const float* __restrict__ emb, const float* __restrict__ gwT2,
    _Float16* __restrict__ W16)
{
    int t = threadIdx.x;
    int n0 = blockIdx.x * 4;
    int y = blockIdx.y;
    const int G = 256/OUT;
    int o = t % OUT, g = t / OUT;
    __shared__ float se[4][EMB];
    if (t < 4*EMB) se[t >> 4][t & 15] = emb[(n0 + (t >> 4))*EMB + (t & 15)];
    __syncthreads();
    for (int kc4 = y*8 + g; kc4 < (y+1)*8; kc4 += G) {
        f32x4 s[4];
#pragma unroll
        for (int ng = 0; ng < 4; ++ng) s[ng] = (f32x4){0.f,0.f,0.f,0.f};
        const float* gp = gwT2 + ((size_t)kc4*OUT + o)*4;
#pragma unroll 4
        for (int e = 0; e < EMB; ++e) {
            f32x4 gv = *(const f32x4*)(gp + (size_t)e*(64*OUT*4));
#pragma unroll
            for (int ng = 0; ng < 4; ++ng) {
                float c = se[ng][e];
                s[ng] += gv * c;
            }
        }
#pragma unroll
        for (int ng = 0; ng < 4; ++ng) {
            f16x4 q;
            q[0] = (_Float16)s[ng][0]; q[1] = (_Float16)s[ng][1];
            q[2] = (_Float16)s[ng][2]; q[3] = (_Float16)s[ng][3];
            *(f16x4*)(W16 + (((size_t)(n0+ng)*64 + kc4)*OUT + o)*4) = q;
        }
    }
}

__global__ __launch_bounds__(256) void bias_k(const float* __restrict__ emb,
                        const float* __restrict__ gbl, float* __restrict__ bn, int OUT)
{
    int idx = blockIdx.x*256 + threadIdx.x;
    if (idx >= N_NODES*OUT) return;
    int n = idx / OUT, o = idx % OUT;
    float s = 0.f;
#pragma unroll
    for (int e = 0; e < EMB; ++e) s += emb[n*EMB + e]*gbl[e*OUT + o];
    bn[idx] = s;
}

// Batched A@x for 8 consecutive steps (x is loop-invariant -> off critical path).
// grid (16,16,8): z = step in batch. Full K=1024, f16 output pAx16 + z*1M.
__global__ __launch_bounds__(256) void gemmaxb_k(
    const _Float16* __restrict__ Ahi, const _Float16* __restrict__ xqT_b,
    _Float16* __restrict__ pAx16)
{
    int st = blockIdx.z;
    const _Float16* BT16 = xqT_b + ((size_t)st << 20);
    _Float16* out = pAx16 + ((size_t)st << 20);
    __shared__ _Float16 Ash[64*72];
    __shared__ _Float16 Bsh[64*72];
    int t = threadIdx.x;
    int l = t & 63, w = t >> 6;
    int wr = w >> 1, wc = w & 1;
    int r0 = blockIdx.y*64, c0 = blockIdx.x*64;
    f32x4 acc[2][2];
#pragma unroll
    for (int i = 0; i < 2; ++i)
#pragma unroll
        for (int j = 0; j < 2; ++j) acc[i][j] = (f32x4){0.f,0.f,0.f,0.f};
    int arow = wr*32 + (l & 15);
    int brow = wc*32 + (l & 15);
    int koff = (l >> 4)*8;
    for (int k0 = 0; k0 < 1024; k0 += 64) {
        __syncthreads();
#pragma unroll
        for (int c = 0; c < 2; ++c) {
            int id = t + 256*c;
            int row = id >> 3, k8 = id & 7;
            *(f16x8*)(&Ash[row*72 + k8*8]) =
                *(const f16x8*)(&Ahi[(size_t)(r0+row)*1024 + k0 + k8*8]);
            *(f16x8*)(&Bsh[row*72 + k8*8]) =
                *(const f16x8*)(&BT16[(size_t)(c0+row)*1024 + k0 + k8*8]);
        }
        __syncthreads();
#pragma unroll
        for (int kk = 0; kk < 2; ++kk) {
            int ko = kk*32 + koff;
            f16x8 ah0 = *(const f16x8*)(&Ash[(size_t)arow*72 + ko]);
            f16x8 ah1 = *(const f16x8*)(&Ash[(size_t)(arow+16)*72 + ko]);
            f16x8 bh0 = *(const f16x8*)(&Bsh[(size_t)brow*72 + ko]);
            f16x8 bh1 = *(const f16x8*)(&Bsh[(size_t)(brow+16)*72 + ko]);
            acc[0][0] = __builtin_amdgcn_mfma_f32_16x16x32_f16(ah0, bh0, acc[0][0], 0, 0, 0);
            acc[0][1] = __builtin_amdgcn_mfma_f32_16x16x32_f16(ah0, bh1, acc[0][1], 0, 0, 0);
            acc[1][0] = __builtin_amdgcn_mfma_f32_16x16x32_f16(ah1, bh0, acc[1][0], 0, 0, 0);
            acc[1][1] = __builtin_amdgcn_mfma_f32_16x16x32_f16(ah1, bh1, acc[1][1], 0, 0, 0);
        }
    }
#pragma unroll
    for (int fr = 0; fr < 2; ++fr)
#pragma unroll
        for (int fc = 0; fc < 2; ++fc) {
            int orow = r0 + wr*32 + fr*16 + ((l >> 4) << 2);
            int ocol = c0 + wc*32 + fc*16 + (l & 15);
#pragma unroll
            for (int i = 0; i < 4; ++i)
                out[(size_t)(orow+i)*1024 + ocol] = (_Float16)acc[fr][fc][i];
        }
}

// Per-step recurrent GEMMs: job 0: A@hT16 -> pAh (f32, split-K pair);
// job 1: A@zhT16 -> pAzh. z = zoff + blockIdx.z in 0..3: job = z>>1, ks = z&1.
__global__ __launch_bounds__(256) void gemm16_k(
    const _Float16* __restrict__ Ahi,
    const _Float16* __restrict__ hT16, const _Float16* __restrict__ zhT16,
    float* __restrict__ pAh, float* __restrict__ pAzh, int zoff)
{
    int z = zoff + blockIdx.z;
    int job = z >> 1, ks = z & 1;
    int kbase = ks << 9;
    float* out = (job ? pAzh : pAh) + ((size_t)ks << 20);
    const _Float16* BT16 = job ? zhT16 : hT16;
    __shared__ _Float16 Ash[64*72];
    __shared__ _Float16 Bsh[64*72];
    int t = threadIdx.x;
    int l = t & 63, w = t >> 6;
    int wr = w >> 1, wc = w & 1;
    int r0 = blockIdx.y*64, c0 = blockIdx.x*64;
    f32x4 acc[2][2];
#pragma unroll
    for (int i = 0; i < 2; ++i)
#pragma unroll
        for (int j = 0; j < 2; ++j) acc[i][j] = (f32x4){0.f,0.f,0.f,0.f};
    int arow = wr*32 + (l & 15);
    int brow = wc*32 + (l & 15);
    int koff = (l >> 4)*8;
    for (int k0 = kbase; k0 < kbase + 512; k0 += 64) {
        __syncthreads();
#pragma unroll
        for (int c = 0; c < 2; ++c) {
            int id = t + 256*c;
            int row = id >> 3, k8 = id & 7;
            *(f16x8*)(&Ash[row*72 + k8*8]) =
                *(const f16x8*)(&Ahi[(size_t)(r0+row)*1024 + k0 + k8*8]);
            *(f16x8*)(&Bsh[row*72 + k8*8]) =
                *(const f16x8*)(&BT16[(size_t)(c0+row)*1024 + k0 + k8*8]);
        }
        __syncthreads();
#pragma unroll
        for (int kk = 0; kk < 2; ++kk) {
            int ko = kk*32 + koff;
            f16x8 ah0 = *(const f16x8*)(&Ash[(size_t)arow*72 + ko]);
            f16x8 ah1 = *(const f16x8*)(&Ash[(size_t)(arow+16)*72 + ko]);
            f16x8 bh0 = *(const f16x8*)(&Bsh[(size_t)brow*72 + ko]);
            f16x8 bh1 = *(const f16x8*)(&Bsh[(size_t)(brow+16)*72 + ko]);
            acc[0][0] = __builtin_amdgcn_mfma_f32_16x16x32_f16(ah0, bh0, acc[0][0], 0, 0, 0);
            acc[0][1] = __builtin_amdgcn_mfma_f32_16x16x32_f16(ah0, bh1, acc[0][1], 0, 0, 0);
            acc[1][0] = __builtin_amdgcn_mfma_f32_16x16x32_f16(ah1, bh0, acc[1][0], 0, 0, 0);
            acc[1][1] = __builtin_amdgcn_mfma_f32_16x16x32_f16(ah1, bh1, acc[1][1], 0, 0, 0);
        }
    }
#pragma unroll
    for (int fr = 0; fr < 2; ++fr)
#pragma unroll
        for (int fc = 0; fc < 2; ++fc) {
            int orow = r0 + wr*32 + fr*16 + ((l >> 4) << 2);
            int ocol = c0 + wc*32 + fc*16 + (l & 15);
#pragma unroll
            for (int i = 0; i < 4; ++i)
                out[(size_t)(orow+i)*1024 + ocol] = acc[fr][fc][i];
        }
}

// zr[n][b][o] = sigmoid([x,h,Ax,Ah]·W(o,:) + bg); writes zhT16[j][n]=z*h.
// Ax read as single f16 (precomputed batch); Ah as split-K f32 pair.
template<int FIRST>
__global__ __launch_bounds__(256) void gate_k(
    const _Float16* __restrict__ xqT16p, const _Float16* __restrict__ pAx16,
    const float* __restrict__ hst, const float* __restrict__ pAh,
    const _Float16* __restrict__ W16, const float* __restrict__ bg,
    float* __restrict__ zr, _Float16* __restrict__ zhT16)
{
    __shared__ float inp[16*256];
    int n = ((blockIdx.x & 7) << 7) | (blockIdx.x >> 3);
    int t = threadIdx.x;
    size_t nb = (size_t)n*1024;
    for (int i = t; i < 1024; i += 256) {
        int b = i >> 6, c = i & 63;
        inp[b*256 + c]       = (float)xqT16p[(size_t)i*1024 + n];
        inp[b*256 + 64 + c]  = FIRST ? 0.f : hst[nb + i];
        inp[b*256 + 128 + c] = (float)pAx16[nb + i];
        inp[b*256 + 192 + c] = FIRST ? 0.f : (pAh[nb + i] + pAh[nb + i + 1048576]);
    }
    __syncthreads();
    int o = t & 127, g = t >> 7;
    const _Float16* wp = W16 + (size_t)n*32768 + o*4;   // [n][kc4][128][4]
    float bias = bg[n*128 + o];
    float acc[8];
#pragma unroll
    for (int u = 0; u < 8; ++u) acc[u] = 0.f;
    for (int k0 = 0; k0 < 256; k0 += 4) {
        f16x4 w4 = *(const f16x4*)(wp + (size_t)(k0 >> 2)*512);
        float w0 = (float)w4[0], w1 = (float)w4[1], w2 = (float)w4[2], w3 = (float)w4[3];
#pragma unroll
        for (int u = 0; u < 8; ++u) {
            float4 iv = *(const float4*)(&inp[(g*8 + u)*256 + k0]);
            acc[u] += w0*iv.x + w1*iv.y + w2*iv.z + w3*iv.w;
        }
    }
#pragma unroll
    for (int u = 0; u < 8; ++u) {
        int b = g*8 + u;
        float pre = acc[u] + bias;
        float val = 1.f/(1.f + expf(-pre));
        zr[((size_t)n*16 + b)*128 + o] = val;
        if (!FIRST && o < 64)
            zhT16[(size_t)(b*64 + o)*1024 + n] = (_Float16)(val * inp[b*256 + 64 + o]);
    }
}

// h_new = r*h + (1-r)*tanh([x, z*h, Ax, Azh]·W + bu); writes hst rows (f32),
// hT16 columns (f16), (WX) next-layer xqT16 columns (f16).
template<int FIRST, int WX>
__global__ __launch_bounds__(256) void upd_k(
    _Float16* __restrict__ xqT16p, const _Float16* __restrict__ pAx16,
    float* __restrict__ hst, const float* __restrict__ pAzh,
    const float* __restrict__ zr, const _Float16* __restrict__ W16,
    const float* __restrict__ bu, _Float16* __restrict__ hT16)
{
    __shared__ float inp[16*256];
    int n = ((blockIdx.x & 7) << 7) | (blockIdx.x >> 3);
    int t = threadIdx.x;
    size_t nb = (size_t)n*1024;
    for (int i = t; i < 1024; i += 256) {
        int b = i >> 6, c = i & 63;
        float hv = FIRST ? 0.f : hst[nb + i];
        float zv = zr[((size_t)n*16 + b)*128 + c];
        inp[b*256 + c]       = (float)xqT16p[(size_t)i*1024 + n];
        inp[b*256 + 64 + c]  = zv * hv;
        inp[b*256 + 128 + c] = (float)pAx16[nb + i];
        inp[b*256 + 192 + c] = FIRST ? 0.f : (pAzh[nb + i] + pAzh[nb + i + 1048576]);
    }
    __syncthreads();
    int o = t & 63, g = t >> 6;
    const _Float16* wp = W16 + (size_t)n*16384 + o*4;   // [n][kc4][64][4]
    float bias = bu[n*64 + o];
    float acc[4];
#pragma unroll
    for (int u = 0; u < 4; ++u) acc[u] = 0.f;
    for (int k0 = 0; k0 < 256; k0 += 4) {
        f16x4 w4 = *(const f16x4*)(wp + (size_t)(k0 >> 2)*256);
        float w0 = (float)w4[0], w1 = (float)w4[1], w2 = (float)w4[2], w3 = (float)w4[3];
#pragma unroll
        for (int u = 0; u < 4; ++u) {
            float4 iv = *(const float4*)(&inp[(g*4 + u)*256 + k0]);
            acc[u] += w0*iv.x + w1*iv.y + w2*iv.z + w3*iv.w;
        }
    }
#pragma unroll
    for (int u = 0; u < 4; ++u) {
        int b = g*4 + u;
        float r = zr[((size_t)n*16 + b)*128 + 64 + o];
        float hold = FIRST ? 0.f : hst[nb + b*64 + o];
        float hc = tanhf(acc[u] + bias);
        float hn = r*hold + (1.f - r)*hc;
        hst[nb + b*64 + o] = hn;
        hT16[(size_t)(b*64 + o)*1024 + n] = (_Float16)hn;
        if (WX) xqT16p[(size_t)(b*64 + o)*1024 + n] = (_Float16)hn;
    }
}

// out[b][o][n] = h[n][b][:]·ecw[o][:] + ecb[o]
__global__ __launch_bounds__(256) void endconv_k(
    const float* __restrict__ hst, const float* __restrict__ ecw,
    const float* __restrict__ ecb, float* __restrict__ out)
{
    int idx = blockIdx.x*256 + threadIdx.x;
    int n = idx & 1023;
    int o = (idx >> 10) % HOR;
    int b = idx / (HOR*1024);
    float s = ecb[o];
#pragma unroll
    for (int hh = 0; hh < 64; ++hh)
        s += hst[((size_t)n*16 + b)*64 + hh] * ecw[o*64 + hh];
    out[idx] = s;
}

extern "C" void kernel_launch(void* const* d_in, const int* in_sizes, int n_in,
                              void* d_out, int out_size, void* d_ws, size_t ws_size,
                              hipStream_t stream)
{
    const float* source = (const float*)d_in[0];
    const float* emb    = (const float*)d_in[2];
    const float* vw     = (const float*)d_in[3];
    const float* gate_w = (const float*)d_in[4];
    const float* gate_b = (const float*)d_in[5];
    const float* upd_w  = (const float*)d_in[6];
    const float* upd_b  = (const float*)d_in[7];
    const float* ecw    = (const float*)d_in[8];
    const float* ecb    = (const float*)d_in[9];
    float* out = (float*)d_out;

    // ---- workspace carve: ~195 MB ----
    char* p = (char*)d_ws;
    _Float16* Ahi = (_Float16*)p; p += (size_t)1048576*2;    //   2.0 MB
    _Float16* WgQ = (_Float16*)p; p += (size_t)33554432*2;   //  64.0 MB [n][64][128][4] f16
    _Float16* WuQ = (_Float16*)p; p += (size_t)16777216*2;   //  32.0 MB [n][64][64][4] f16
    float* bgn  = (float*)p;  p += (size_t)131072*4;         //   0.5 MB
    float* bun  = (float*)p;  p += (size_t)65536*4;          //   0.25 MB
    _Float16* xqT = (_Float16*)p; p += (size_t)25165824*2;   //  48.0 MB [p][j][n] f16
    float* hbuf = (float*)p;  p += (size_t)1048576*4;        //   4.0 MB h rows f32
    _Float16* hT16 = (_Float16*)p; p += (size_t)1048576*2;   //   2.0 MB h cols f16
    float* zrb  = (float*)p;  p += (size_t)2097152*4;        //   8.0 MB
    _Float16* zhT16 = (_Float16*)p; p += (size_t)1048576*2;  //   2.0 MB (z*h)^T f16
    float* pAh  = (float*)p;  p += (size_t)2097152*4;        //   8.0 MB split-K pair
    _Float16* pAx16 = (_Float16*)p; p += (size_t)8388608*2;  //  16.0 MB 8-step A@x batch
    float* pAzh = (float*)p;  p += (size_t)2097152*4;        //   8.0 MB split-K pair
    float* gwT2 = pAzh;   // 2 MB scratch, aliases pAzh (dead during layer setup)

    embedq6_k<<<dim3(16,24,2), 256, 0, stream>>>(source, vw, xqT);
    adj_k<<<1024, 256, 0, stream>>>(emb, Ahi);

    for (int l = 0; l < 2; ++l) {
        wtrans2_k<128><<<2048, 256, 0, stream>>>(gate_w + (size_t)l*524288, gwT2);
        wnodeq3_k<128><<<dim3(256,8), 256, 0, stream>>>(emb, gwT2, WgQ);
        wtrans2_k<64><<<1024, 256, 0, stream>>>(upd_w + (size_t)l*262144, gwT2);
        wnodeq3_k<64><<<dim3(256,8), 256, 0, stream>>>(emb, gwT2, WuQ);
        bias_k<<<512, 256, 0, stream>>>(emb, gate_b + l*2048, bgn, 128);
        bias_k<<<256, 256, 0, stream>>>(emb, upd_b + l*1024, bun, 64);
        for (int ps = 0; ps < PWIN; ++ps) {
            _Float16* xqT_p = xqT + ((size_t)ps << 20);
            _Float16* pAx_p = pAx16 + ((size_t)(ps & 7) << 20);
            if ((ps & 7) == 0)
                gemmaxb_k<<<dim3(16,16,8), 256, 0, stream>>>(Ahi, xqT_p, pAx16);
            if (ps == 0) {
                gate_k<1><<<1024, 256, 0, stream>>>(xqT_p, pAx_p, hbuf, pAh, WgQ, bgn, zrb, zhT16);
                if (l == 0)
                    upd_k<1,1><<<1024, 256, 0, stream>>>(xqT_p, pAx_p, hbuf, pAzh, zrb, WuQ, bun, hT16);
                else
                    upd_k<1,0><<<1024, 256, 0, stream>>>(xqT_p, pAx_p, hbuf, pAzh, zrb, WuQ, bun, hT16);
            } else {
                gemm16_k<<<dim3(16,16,2), 256, 0, stream>>>(Ahi, hT16, zhT16, pAh, pAzh, 0);
                gate_k<0><<<1024, 256, 0, stream>>>(xqT_p, pAx_p, hbuf, pAh, WgQ, bgn, zrb, zhT16);
                gemm16_k<<<dim3(16,16,2), 256, 0, stream>>>(Ahi, hT16, zhT16, pAh, pAzh, 2);
                if (l == 0)
                    upd_k<0,1><<<1024, 256, 0, stream>>>(xqT_p, pAx_p, hbuf, pAzh, zrb, WuQ, bun, hT16);
                else
                    upd_k<0,0><<<1024, 256, 0, stream>>>(xqT_p, pAx_p, hbuf, pAzh, zrb, WuQ, bun, hT16);
            }
        }
    }
    endconv_k<<<768, 256, 0, stream>>>(hbuf, ecw, ecb, out);
}